// Round 10
// baseline (1139.212 us; speedup 1.0000x reference)
//
#include <hip/hip_runtime.h>
#include <hip/hip_bf16.h>

#define E_TOT   100000
#define N_NODES 10000
#define DIMV    80
#define HID     64
#define EDIM    32
#define WNUM    2304
#define TE      32

static constexpr float NORMF      = 0.14433756729740643f;  // 1/sqrt(48)
static constexpr float INV_SQRT3F = 0.57735026918962576f;
static constexpr float RS32       = 0.17677669529663687f;  // 1/sqrt(32)
static constexpr float RS16       = 0.25f;                 // 1/sqrt(16)

typedef __attribute__((ext_vector_type(8))) short bf16x8;
typedef __attribute__((ext_vector_type(4))) float f32x4;

static __device__ __forceinline__ ushort f2bf(float v) {
    __hip_bfloat16 h(v);
    return *reinterpret_cast<ushort*>(&h);
}

// Coalesced transpose + bf16 convert: W2 (HID x WNUM fp32) -> W2T (WNUM x HID bf16)
__global__ __launch_bounds__(256) void prep_w2t(const float* __restrict__ W2,
                                                ushort* __restrict__ W2T) {
    __shared__ float sT[64][65];
    const int j0 = blockIdx.x * 64;
    #pragma unroll
    for (int k = 0; k < 16; ++k) {
        int idx = threadIdx.x + k*256;
        int t = idx >> 6, j = idx & 63;
        sT[j][t] = W2[t*WNUM + j0 + j];
    }
    __syncthreads();
    #pragma unroll
    for (int k = 0; k < 16; ++k) {
        int idx = threadIdx.x + k*256;
        int j = idx >> 6, t = idx & 63;
        W2T[(size_t)(j0 + j)*64 + t] = f2bf(sT[j][t]);
    }
}

// Edge kernel, round-8 structure, templated for ablation.
// DEPTH: B-prefetch ring depth. MODE: 0 normal, 1 no-global-loads-in-loop
// (reuse slot-0 regs, asm-pinned), 2 no-epilogue (register adds only).
template<int DEPTH, int MODE>
__global__ __launch_bounds__(256) void edge_kernel(
    const int* __restrict__ dst, const float* __restrict__ x_src,
    const float* __restrict__ sh, const float* __restrict__ ea,
    const float* __restrict__ W1, const float* __restrict__ b1,
    const ushort* __restrict__ W2T, const float* __restrict__ b2,
    float* __restrict__ sums, float* __restrict__ cnt)
{
    __shared__ float  sX[TE][81];
    __shared__ float  sSh[TE][4];
    __shared__ float  sXs1[TE][17];
    __shared__ float  sEcA[TE][33];
    __shared__ ushort sHbf[TE][HID];
    __shared__ float  sMsg[TE][84];
    __shared__ int    sDst[TE];

    const int tid  = threadIdx.x;
    const int lane = tid & 63;
    const int wave = tid >> 6;
    const int e0   = blockIdx.x * TE;

    for (int i = tid; i < TE*DIMV; i += 256) { int e = i/80, k = i-e*80; sX[e][k] = x_src[e0*DIMV + i]; }
    for (int i = tid; i < TE*EDIM; i += 256) { int e = i>>5, k = i&31; sEcA[e][k] = ea[e0*EDIM + i]; }
    for (int i = tid; i < TE*4;    i += 256) sSh[0][i] = sh[e0*4 + i];
    if (tid < TE) sDst[tid] = dst[e0 + tid];
    __syncthreads();

    // layer 1: H = relu(ea @ W1 + b1)
    #pragma unroll
    for (int k = 0; k < (TE*HID)/256; ++k) {
        int idx = tid + k*256;
        int e = idx >> 6, t = idx & 63;
        float h = b1[t];
        #pragma unroll
        for (int i = 0; i < EDIM; ++i) h = fmaf(sEcA[e][i], W1[i*HID + t], h);
        sHbf[e][t] = f2bf(fmaxf(h, 0.f));
    }
    __syncthreads();

    for (int i = tid; i < TE*32; i += 256) {
        int e = i >> 5, u = i & 31;
        sEcA[e][u] = sSh[e][0] * sX[e][u];           // cA
    }
    for (int i = tid; i < TE*16; i += 256) {
        int e = i >> 4, u = i & 15;
        sXs1[e][u] = INV_SQRT3F * (sX[e][32+u*3+0]*sSh[e][1] +
                                   sX[e][32+u*3+1]*sSh[e][2] +
                                   sX[e][32+u*3+2]*sSh[e][3]);
    }
    for (int i = tid; i < TE*84; i += 256) sMsg[0][i] = 0.f;
    __syncthreads();

    const int c     = lane & 15;
    const int g     = lane >> 4;
    const int rbase = g << 2;
    bf16x8 afrag[2][2];
    #pragma unroll
    for (int rt = 0; rt < 2; ++rt)
        #pragma unroll
        for (int kt = 0; kt < 2; ++kt)
            afrag[rt][kt] = *reinterpret_cast<const bf16x8*>(&sHbf[rt*16 + c][kt*32 + g*8]);

    float pA[8]     = {};
    float sC2[8]    = {};
    float sDv[8][3] = {};

    // ---- B prefetch ring (DEPTH slots), tiles t16 = wave + 4k
    bf16x8 pb0[DEPTH], pb1[DEPTH];
    float  pbv[DEPTH];
    #pragma unroll
    for (int d = 0; d < DEPTH; ++d) {
        const int t16 = wave + (d << 2);
        const ushort* bp = W2T + (((size_t)((t16 << 4) + c)) << 6) + (g << 3);
        pb0[d] = *reinterpret_cast<const bf16x8*>(bp);
        pb1[d] = *reinterpret_cast<const bf16x8*>(bp + 32);
        pbv[d] = b2[(t16 << 4) + c];
    }

    #pragma unroll
    for (int k = 0; k < 36; ++k) {
        const int slot = (MODE == 1) ? 0 : (k % DEPTH);   // static under full unroll
        bf16x8 cb0 = pb0[slot];
        bf16x8 cb1 = pb1[slot];
        float  cbv = pbv[slot];
        if (MODE == 1) {
            // opaque touch: prevents MFMA hoisting/CSE while issuing 0 instructions
            asm volatile("" : "+v"(cb0), "+v"(cb1), "+v"(cbv));
        } else if (k + DEPTH < 36) {
            const int t16n = wave + ((k + DEPTH) << 2);
            const ushort* bp = W2T + (((size_t)((t16n << 4) + c)) << 6) + (g << 3);
            pb0[slot] = *reinterpret_cast<const bf16x8*>(bp);
            pb1[slot] = *reinterpret_cast<const bf16x8*>(bp + 32);
            pbv[slot] = b2[(t16n << 4) + c];
        }
        f32x4 a0 = {cbv, cbv, cbv, cbv};
        f32x4 a1 = {cbv, cbv, cbv, cbv};
        a0 = __builtin_amdgcn_mfma_f32_16x16x32_bf16(afrag[0][0], cb0, a0, 0, 0, 0);
        a0 = __builtin_amdgcn_mfma_f32_16x16x32_bf16(afrag[0][1], cb1, a0, 0, 0, 0);
        a1 = __builtin_amdgcn_mfma_f32_16x16x32_bf16(afrag[1][0], cb0, a1, 0, 0, 0);
        a1 = __builtin_amdgcn_mfma_f32_16x16x32_bf16(afrag[1][1], cb1, a1, 0, 0, 0);

        if (MODE == 2) {
            #pragma unroll
            for (int r = 0; r < 4; ++r) { pA[r] += a0[r]; pA[4+r] += a1[r]; }
            continue;
        }

        const int t16 = wave + (k << 2);
        if (k < 16) {            // wa
            const int u = t16 >> 1;
            #pragma unroll
            for (int r = 0; r < 4; ++r) {
                pA[r]   = fmaf(sEcA[rbase + r][u],      a0[r], pA[r]);
                pA[4+r] = fmaf(sEcA[16 + rbase + r][u], a1[r], pA[4+r]);
            }
        } else if (k < 24) {     // wc
            const int u = t16 - 64;
            #pragma unroll
            for (int r = 0; r < 4; ++r) {
                sC2[r]   = fmaf(sX[rbase + r][u],      a0[r], sC2[r]);
                sC2[4+r] = fmaf(sX[16 + rbase + r][u], a1[r], sC2[4+r]);
            }
        } else if (k < 28) {     // wd
            const int u = t16 - 96;
            #pragma unroll
            for (int r = 0; r < 4; ++r) {
                #pragma unroll
                for (int m = 0; m < 3; ++m) {
                    sDv[r][m]   = fmaf(sX[rbase + r][32 + u*3 + m],      a0[r], sDv[r][m]);
                    sDv[4+r][m] = fmaf(sX[16 + rbase + r][32 + u*3 + m], a1[r], sDv[4+r][m]);
                }
            }
        } else {                 // wb
            const int u = (t16 - 112) >> 1;
            #pragma unroll
            for (int r = 0; r < 4; ++r) {
                pA[r]   = fmaf(sXs1[rbase + r][u],      a0[r], pA[r]);
                pA[4+r] = fmaf(sXs1[16 + rbase + r][u], a1[r], pA[4+r]);
            }
        }
    }

    const int wcol = c + ((wave & 1) << 4);
    #pragma unroll
    for (int rt = 0; rt < 2; ++rt) {
        #pragma unroll
        for (int r = 0; r < 4; ++r) {
            const int e = rt*16 + rbase + r;
            const int s = rt*4 + r;
            atomicAdd(&sMsg[e][wcol], pA[s]);
            const float s0 = sSh[e][0];
            atomicAdd(&sMsg[e][32 + c*3 + 0], sSh[e][1]*sC2[s] + s0*sDv[s][0]);
            atomicAdd(&sMsg[e][32 + c*3 + 1], sSh[e][2]*sC2[s] + s0*sDv[s][1]);
            atomicAdd(&sMsg[e][32 + c*3 + 2], sSh[e][3]*sC2[s] + s0*sDv[s][2]);
        }
    }
    __syncthreads();

    for (int i = tid; i < TE*DIMV; i += 256) {
        int e = i / DIMV, k = i - e*DIMV;
        atomicAdd(&sums[sDst[e]*DIMV + k], NORMF * sMsg[e][k]);
    }
    if (tid < TE) atomicAdd(&cnt[sDst[tid]], 1.0f);
}

// Node kernel: out = residual + sums/max(cnt,1)
__global__ __launch_bounds__(256) void node_kernel(
    const float* __restrict__ x_dst, const float* __restrict__ rw0,
    const float* __restrict__ rw1, const float* __restrict__ sums,
    const float* __restrict__ cnt, float* __restrict__ out)
{
    int gid = blockIdx.x*256 + threadIdx.x;
    if (gid >= N_NODES*DIMV) return;
    int n = gid / DIMV;
    int k = gid - n*DIMV;
    const float* xd = x_dst + n*DIMV;
    float r = 0.f;
    if (k < 32) {
        #pragma unroll
        for (int u = 0; u < 32; ++u) r = fmaf(xd[u], rw0[u*32 + k], r);
        r *= RS32;
    } else {
        int kk = k - 32;
        int w = kk / 3, m = kk - w*3;
        #pragma unroll
        for (int u = 0; u < 16; ++u) r = fmaf(xd[32 + u*3 + m], rw1[u*16 + w], r);
        r *= RS16;
    }
    float cc = cnt[n];
    out[gid] = r + sums[gid] / fmaxf(cc, 1.f);
}

extern "C" void kernel_launch(void* const* d_in, const int* in_sizes, int n_in,
                              void* d_out, int out_size, void* d_ws, size_t ws_size,
                              hipStream_t stream) {
    const int*   dst   = (const int*)  d_in[0];
    const float* x_src = (const float*)d_in[1];
    const float* x_dst = (const float*)d_in[2];
    const float* sh    = (const float*)d_in[3];
    const float* ea    = (const float*)d_in[4];
    const float* W1    = (const float*)d_in[5];
    const float* b1    = (const float*)d_in[6];
    const float* W2    = (const float*)d_in[7];
    const float* b2    = (const float*)d_in[8];
    const float* rw0   = (const float*)d_in[9];
    const float* rw1   = (const float*)d_in[10];
    float* out  = (float*)d_out;
    char*  ws   = (char*)d_ws;

    const size_t sumsN = (size_t)N_NODES*DIMV;
    float*  sums = (float*)ws;                               // 3.2 MB
    float*  cnt  = sums + sumsN;                             // 40 KB
    ushort* W2T  = (ushort*)(ws + (sumsN + N_NODES)*4);      // 0.3 MB
    char*   ws2  = (char*)(W2T + (size_t)WNUM*HID);
    float*  sums2 = (float*)ws2;                             // scratch for ablation
    float*  cnt2  = sums2 + sumsN;
    const size_t need_abl = (size_t)((char*)(cnt2 + N_NODES) - ws);

    hipMemsetAsync(ws, 0, (sumsN + N_NODES)*4, stream);
    prep_w2t<<<WNUM/64, 256, 0, stream>>>(W2, W2T);
    // real path (round-8 structure, DEPTH=1)
    edge_kernel<1,0><<<E_TOT/TE, 256, 0, stream>>>(dst, x_src, sh, ea, W1, b1, W2T, b2, sums, cnt);
    if (need_abl <= ws_size) {   // diagnostic variants into scratch (launch-invariant branch)
        edge_kernel<1,1><<<E_TOT/TE, 256, 0, stream>>>(dst, x_src, sh, ea, W1, b1, W2T, b2, sums2, cnt2);
        edge_kernel<1,2><<<E_TOT/TE, 256, 0, stream>>>(dst, x_src, sh, ea, W1, b1, W2T, b2, sums2, cnt2);
        edge_kernel<4,0><<<E_TOT/TE, 256, 0, stream>>>(dst, x_src, sh, ea, W1, b1, W2T, b2, sums2, cnt2);
    }
    node_kernel<<<(N_NODES*DIMV + 255)/256, 256, 0, stream>>>(x_dst, rw0, rw1, sums, cnt, out);
}

// Round 11
// 435.430 us; speedup vs baseline: 2.6163x; 2.6163x over previous
//
#include <hip/hip_runtime.h>
#include <hip/hip_bf16.h>

#define E_TOT   100000
#define N_NODES 10000
#define DIMV    80
#define HID     64
#define EDIM    32
#define WNUM    2304
#define TE      32

static constexpr float NORMF      = 0.14433756729740643f;  // 1/sqrt(48)
static constexpr float INV_SQRT3F = 0.57735026918962576f;
static constexpr float RS32       = 0.17677669529663687f;  // 1/sqrt(32)
static constexpr float RS16       = 0.25f;                 // 1/sqrt(16)

typedef __attribute__((ext_vector_type(8))) short bf16x8;
typedef __attribute__((ext_vector_type(4))) float f32x4;

static __device__ __forceinline__ ushort f2bf(float v) {
    __hip_bfloat16 h(v);
    return *reinterpret_cast<ushort*>(&h);
}
static __device__ __forceinline__ float bf2f(ushort u) {
    unsigned int w = ((unsigned int)u) << 16;
    return __builtin_bit_cast(float, w);
}

// W2 (HID x WNUM fp32) -> W2T (WNUM x HID bf16), coalesced via LDS transpose
__global__ __launch_bounds__(256) void prep_w2t(const float* __restrict__ W2,
                                                ushort* __restrict__ W2T) {
    __shared__ float sT[64][65];
    const int j0 = blockIdx.x * 64;
    #pragma unroll
    for (int k = 0; k < 16; ++k) {
        int idx = threadIdx.x + k*256;
        int t = idx >> 6, j = idx & 63;
        sT[j][t] = W2[t*WNUM + j0 + j];
    }
    __syncthreads();
    #pragma unroll
    for (int k = 0; k < 16; ++k) {
        int idx = threadIdx.x + k*256;
        int j = idx >> 6, t = idx & 63;
        W2T[(size_t)(j0 + j)*64 + t] = f2bf(sT[j][t]);
    }
}

// ---- CSR build ----
__global__ __launch_bounds__(256) void hist_kernel(const int* __restrict__ dst,
                                                   int* __restrict__ hist) {
    int e = blockIdx.x*256 + threadIdx.x;
    if (e < E_TOT) atomicAdd(&hist[dst[e]], 1);
}

__global__ __launch_bounds__(256) void scan_kernel(const int* __restrict__ hist,
                                                   int* __restrict__ offs,
                                                   float* __restrict__ cntf) {
    __shared__ int part[256];
    const int t = threadIdx.x;
    const int base = t * 40;
    int s = 0;
    for (int i = 0; i < 40; ++i) { int n = base + i; if (n < N_NODES) s += hist[n]; }
    part[t] = s; __syncthreads();
    for (int d = 1; d < 256; d <<= 1) {
        int v = 0; if (t >= d) v = part[t - d];
        __syncthreads();
        if (t >= d) part[t] += v;
        __syncthreads();
    }
    int run = (t > 0) ? part[t-1] : 0;
    for (int i = 0; i < 40; ++i) {
        int n = base + i;
        if (n < N_NODES) {
            offs[n] = run;
            int h = hist[n];
            run += h;
            cntf[n] = (float)(h > 0 ? h : 1);
        }
    }
}

__global__ __launch_bounds__(256) void scatter_kernel(const int* __restrict__ dst,
                                                      int* __restrict__ cursor,
                                                      const int* __restrict__ offs,
                                                      int* __restrict__ eidx) {
    int e = blockIdx.x*256 + threadIdx.x;
    if (e < E_TOT) {
        int d = dst[e];
        int p = atomicAdd(&cursor[d], 1);
        eidx[offs[d] + p] = e;
    }
}

// Edge kernel, r8 structure. ATOMIC=1: global atomic scatter into sums/cnt
// (fallback). ATOMIC=0: ZERO global atomics — coalesced bf16 store of
// per-edge messages (NORM folded).
template<int ATOMIC>
__global__ __launch_bounds__(256) void edge_kernel(
    const int* __restrict__ dst, const float* __restrict__ x_src,
    const float* __restrict__ sh, const float* __restrict__ ea,
    const float* __restrict__ W1, const float* __restrict__ b1,
    const ushort* __restrict__ W2T, const float* __restrict__ b2,
    float* __restrict__ sums, float* __restrict__ cnt,
    ushort* __restrict__ msg)
{
    __shared__ float  sX[TE][81];
    __shared__ float  sSh[TE][4];
    __shared__ float  sXs1[TE][17];
    __shared__ float  sEcA[TE][33];
    __shared__ ushort sHbf[TE][HID];
    __shared__ float  sMsg[TE][84];
    __shared__ int    sDst[TE];

    const int tid  = threadIdx.x;
    const int lane = tid & 63;
    const int wave = tid >> 6;
    const int e0   = blockIdx.x * TE;

    for (int i = tid; i < TE*DIMV; i += 256) { int e = i/80, k = i-e*80; sX[e][k] = x_src[e0*DIMV + i]; }
    for (int i = tid; i < TE*EDIM; i += 256) { int e = i>>5, k = i&31; sEcA[e][k] = ea[e0*EDIM + i]; }
    for (int i = tid; i < TE*4;    i += 256) sSh[0][i] = sh[e0*4 + i];
    if (ATOMIC) { if (tid < TE) sDst[tid] = dst[e0 + tid]; }
    __syncthreads();

    // layer 1: H = relu(ea @ W1 + b1)
    #pragma unroll
    for (int k = 0; k < (TE*HID)/256; ++k) {
        int idx = tid + k*256;
        int e = idx >> 6, t = idx & 63;
        float h = b1[t];
        #pragma unroll
        for (int i = 0; i < EDIM; ++i) h = fmaf(sEcA[e][i], W1[i*HID + t], h);
        sHbf[e][t] = f2bf(fmaxf(h, 0.f));
    }
    __syncthreads();

    for (int i = tid; i < TE*32; i += 256) {
        int e = i >> 5, u = i & 31;
        sEcA[e][u] = sSh[e][0] * sX[e][u];           // cA
    }
    for (int i = tid; i < TE*16; i += 256) {
        int e = i >> 4, u = i & 15;
        sXs1[e][u] = INV_SQRT3F * (sX[e][32+u*3+0]*sSh[e][1] +
                                   sX[e][32+u*3+1]*sSh[e][2] +
                                   sX[e][32+u*3+2]*sSh[e][3]);
    }
    for (int i = tid; i < TE*84; i += 256) sMsg[0][i] = 0.f;
    __syncthreads();

    const int c     = lane & 15;
    const int g     = lane >> 4;
    const int rbase = g << 2;
    bf16x8 afrag[2][2];
    #pragma unroll
    for (int rt = 0; rt < 2; ++rt)
        #pragma unroll
        for (int kt = 0; kt < 2; ++kt)
            afrag[rt][kt] = *reinterpret_cast<const bf16x8*>(&sHbf[rt*16 + c][kt*32 + g*8]);

    float pA[8]     = {};
    float sC2[8]    = {};
    float sDv[8][3] = {};

    // 1-deep B prefetch, fully-unrolled 36-tile loop (r8 structure)
    bf16x8 nb0, nb1;
    float  nbv;
    {
        const ushort* bp = W2T + (((size_t)((wave << 4) + c)) << 6) + (g << 3);
        nb0 = *reinterpret_cast<const bf16x8*>(bp);
        nb1 = *reinterpret_cast<const bf16x8*>(bp + 32);
        nbv = b2[(wave << 4) + c];
    }
    #pragma unroll
    for (int k = 0; k < 36; ++k) {
        const bf16x8 cb0 = nb0;
        const bf16x8 cb1 = nb1;
        const float  cbv = nbv;
        if (k < 35) {
            const int t16n = wave + ((k + 1) << 2);
            const ushort* bp = W2T + (((size_t)((t16n << 4) + c)) << 6) + (g << 3);
            nb0 = *reinterpret_cast<const bf16x8*>(bp);
            nb1 = *reinterpret_cast<const bf16x8*>(bp + 32);
            nbv = b2[(t16n << 4) + c];
        }
        f32x4 a0 = {cbv, cbv, cbv, cbv};
        f32x4 a1 = {cbv, cbv, cbv, cbv};
        a0 = __builtin_amdgcn_mfma_f32_16x16x32_bf16(afrag[0][0], cb0, a0, 0, 0, 0);
        a0 = __builtin_amdgcn_mfma_f32_16x16x32_bf16(afrag[0][1], cb1, a0, 0, 0, 0);
        a1 = __builtin_amdgcn_mfma_f32_16x16x32_bf16(afrag[1][0], cb0, a1, 0, 0, 0);
        a1 = __builtin_amdgcn_mfma_f32_16x16x32_bf16(afrag[1][1], cb1, a1, 0, 0, 0);

        const int t16 = wave + (k << 2);
        if (k < 16) {            // wa
            const int u = t16 >> 1;
            #pragma unroll
            for (int r = 0; r < 4; ++r) {
                pA[r]   = fmaf(sEcA[rbase + r][u],      a0[r], pA[r]);
                pA[4+r] = fmaf(sEcA[16 + rbase + r][u], a1[r], pA[4+r]);
            }
        } else if (k < 24) {     // wc
            const int u = t16 - 64;
            #pragma unroll
            for (int r = 0; r < 4; ++r) {
                sC2[r]   = fmaf(sX[rbase + r][u],      a0[r], sC2[r]);
                sC2[4+r] = fmaf(sX[16 + rbase + r][u], a1[r], sC2[4+r]);
            }
        } else if (k < 28) {     // wd
            const int u = t16 - 96;
            #pragma unroll
            for (int r = 0; r < 4; ++r) {
                #pragma unroll
                for (int m = 0; m < 3; ++m) {
                    sDv[r][m]   = fmaf(sX[rbase + r][32 + u*3 + m],      a0[r], sDv[r][m]);
                    sDv[4+r][m] = fmaf(sX[16 + rbase + r][32 + u*3 + m], a1[r], sDv[4+r][m]);
                }
            }
        } else {                 // wb
            const int u = (t16 - 112) >> 1;
            #pragma unroll
            for (int r = 0; r < 4; ++r) {
                pA[r]   = fmaf(sXs1[rbase + r][u],      a0[r], pA[r]);
                pA[4+r] = fmaf(sXs1[16 + rbase + r][u], a1[r], pA[4+r]);
            }
        }
    }

    const int wcol = c + ((wave & 1) << 4);
    #pragma unroll
    for (int rt = 0; rt < 2; ++rt) {
        #pragma unroll
        for (int r = 0; r < 4; ++r) {
            const int e = rt*16 + rbase + r;
            const int s = rt*4 + r;
            atomicAdd(&sMsg[e][wcol], pA[s]);
            const float s0 = sSh[e][0];
            atomicAdd(&sMsg[e][32 + c*3 + 0], sSh[e][1]*sC2[s] + s0*sDv[s][0]);
            atomicAdd(&sMsg[e][32 + c*3 + 1], sSh[e][2]*sC2[s] + s0*sDv[s][1]);
            atomicAdd(&sMsg[e][32 + c*3 + 2], sSh[e][3]*sC2[s] + s0*sDv[s][2]);
        }
    }
    __syncthreads();

    if (ATOMIC) {
        for (int i = tid; i < TE*DIMV; i += 256) {
            int e = i / DIMV, k = i - e*DIMV;
            atomicAdd(&sums[sDst[e]*DIMV + k], NORMF * sMsg[e][k]);
        }
        if (tid < TE) atomicAdd(&cnt[sDst[tid]], 1.0f);
    } else {
        // coalesced bf16 store of per-edge messages, NORM folded
        for (int i = tid; i < (TE*DIMV)/2; i += 256) {
            int e = i / 40, p = i - e*40;
            unsigned int lo = f2bf(NORMF * sMsg[e][p*2 + 0]);
            unsigned int hi = f2bf(NORMF * sMsg[e][p*2 + 1]);
            reinterpret_cast<unsigned int*>(msg)[(size_t)(e0 + e)*40 + p] = lo | (hi << 16);
        }
    }
}

// CSR node kernel: residual + mean of gathered bf16 messages
__global__ __launch_bounds__(256) void node_gather_kernel(
    const float* __restrict__ x_dst, const float* __restrict__ rw0,
    const float* __restrict__ rw1, const ushort* __restrict__ msg,
    const int* __restrict__ offs, const int* __restrict__ eidx,
    const float* __restrict__ cntf, const int* __restrict__ hist,
    float* __restrict__ out)
{
    int gid = blockIdx.x*256 + threadIdx.x;
    if (gid >= N_NODES*DIMV) return;
    int n = gid / DIMV;
    int k = gid - n*DIMV;
    const float* xd = x_dst + n*DIMV;
    float r = 0.f;
    if (k < 32) {
        #pragma unroll
        for (int u = 0; u < 32; ++u) r = fmaf(xd[u], rw0[u*32 + k], r);
        r *= RS32;
    } else {
        int kk = k - 32;
        int w = kk / 3, m = kk - w*3;
        #pragma unroll
        for (int u = 0; u < 16; ++u) r = fmaf(xd[32 + u*3 + m], rw1[u*16 + w], r);
        r *= RS16;
    }
    float s = 0.f;
    const int o = offs[n], d = hist[n];
    for (int j = 0; j < d; ++j) s += bf2f(msg[(size_t)eidx[o + j]*DIMV + k]);
    out[gid] = r + s / cntf[n];
}

// Fallback node kernel (atomic path)
__global__ __launch_bounds__(256) void node_kernel(
    const float* __restrict__ x_dst, const float* __restrict__ rw0,
    const float* __restrict__ rw1, const float* __restrict__ sums,
    const float* __restrict__ cnt, float* __restrict__ out)
{
    int gid = blockIdx.x*256 + threadIdx.x;
    if (gid >= N_NODES*DIMV) return;
    int n = gid / DIMV;
    int k = gid - n*DIMV;
    const float* xd = x_dst + n*DIMV;
    float r = 0.f;
    if (k < 32) {
        #pragma unroll
        for (int u = 0; u < 32; ++u) r = fmaf(xd[u], rw0[u*32 + k], r);
        r *= RS32;
    } else {
        int kk = k - 32;
        int w = kk / 3, m = kk - w*3;
        #pragma unroll
        for (int u = 0; u < 16; ++u) r = fmaf(xd[32 + u*3 + m], rw1[u*16 + w], r);
        r *= RS16;
    }
    float cc = cnt[n];
    out[gid] = r + sums[gid] / fmaxf(cc, 1.f);
}

extern "C" void kernel_launch(void* const* d_in, const int* in_sizes, int n_in,
                              void* d_out, int out_size, void* d_ws, size_t ws_size,
                              hipStream_t stream) {
    const int*   dst   = (const int*)  d_in[0];
    const float* x_src = (const float*)d_in[1];
    const float* x_dst = (const float*)d_in[2];
    const float* sh    = (const float*)d_in[3];
    const float* ea    = (const float*)d_in[4];
    const float* W1    = (const float*)d_in[5];
    const float* b1    = (const float*)d_in[6];
    const float* W2    = (const float*)d_in[7];
    const float* b2    = (const float*)d_in[8];
    const float* rw0   = (const float*)d_in[9];
    const float* rw1   = (const float*)d_in[10];
    float* out = (float*)d_out;
    char*  ws  = (char*)d_ws;

    size_t off = 0;
    auto alloc = [&](size_t bytes) { size_t o = off; off = (off + bytes + 255) & ~255ULL; return o; };
    size_t o_w2t  = alloc((size_t)WNUM*HID*2);          // 0.29 MB
    size_t o_hist = alloc((size_t)N_NODES*4);
    size_t o_offs = alloc((size_t)N_NODES*4);
    size_t o_cur  = alloc((size_t)N_NODES*4);
    size_t o_cntf = alloc((size_t)N_NODES*4);
    size_t o_eidx = alloc((size_t)E_TOT*4);             // 0.4 MB
    size_t o_msg  = alloc((size_t)E_TOT*DIMV*2);        // 16 MB
    const bool no_atomic = (off <= ws_size);            // ~16.9 MB total

    ushort* W2T = (ushort*)(ws + o_w2t);

    if (no_atomic) {
        int*    histp = (int*)   (ws + o_hist);
        int*    offsp = (int*)   (ws + o_offs);
        int*    curp  = (int*)   (ws + o_cur);
        float*  cntf  = (float*) (ws + o_cntf);
        int*    eidx  = (int*)   (ws + o_eidx);
        ushort* msg   = (ushort*)(ws + o_msg);

        hipMemsetAsync(histp, 0, (size_t)N_NODES*4, stream);
        hipMemsetAsync(curp,  0, (size_t)N_NODES*4, stream);
        prep_w2t<<<WNUM/64, 256, 0, stream>>>(W2, W2T);
        hist_kernel<<<(E_TOT + 255)/256, 256, 0, stream>>>(dst, histp);
        scan_kernel<<<1, 256, 0, stream>>>(histp, offsp, cntf);
        scatter_kernel<<<(E_TOT + 255)/256, 256, 0, stream>>>(dst, curp, offsp, eidx);
        edge_kernel<0><<<E_TOT/TE, 256, 0, stream>>>(dst, x_src, sh, ea, W1, b1,
                                                     W2T, b2, nullptr, nullptr, msg);
        node_gather_kernel<<<(N_NODES*DIMV + 255)/256, 256, 0, stream>>>(
            x_dst, rw0, rw1, msg, offsp, eidx, cntf, histp, out);
    } else {
        float* sums = (float*)(ws + o_hist);            // reuse space past W2T
        float* cnt  = sums + (size_t)N_NODES*DIMV;
        hipMemsetAsync(sums, 0, (size_t)(N_NODES*DIMV + N_NODES)*4, stream);
        prep_w2t<<<WNUM/64, 256, 0, stream>>>(W2, W2T);
        edge_kernel<1><<<E_TOT/TE, 256, 0, stream>>>(dst, x_src, sh, ea, W1, b1,
                                                     W2T, b2, sums, cnt, nullptr);
        node_kernel<<<(N_NODES*DIMV + 255)/256, 256, 0, stream>>>(x_dst, rw0, rw1, sums, cnt, out);
    }
}